// Round 8
// baseline (299.573 us; speedup 1.0000x reference)
//
#include <hip/hip_runtime.h>

// ---------------- problem constants ----------------
#define NLAT 1228760
#define RATE_OFF 5529600      // 2*3*921600
#define BPD_OFF 6758360
#define NB_ARM 4800           // ceil(NLAT/256)
#define LSC 13.8155f

typedef float v2f __attribute__((ext_vector_type(2)));

// grid sizes: (720,1280)(360,640)(180,320)(90,160)(45,80)(23,40)(12,20)
static __device__ const int d_GOFF[8] = {0,921600,1152000,1209600,1224000,1227600,1228520,1228760};
static __device__ const int d_GW[7]   = {1280,640,320,160,80,40,20};
static __device__ const int d_XOFF[7] = {0,6451200,7833600,8121600,8179200,8190000,8191840};

#define S1_OFF   9574480   // 6*921600
#define BSUM_OFF 15104080  // NB_ARM partial sums
// s2 reuses x0 buffer (offset 0, 6451200 >= 5529600)

// 24 causal context offsets
static __device__ const int d_DR[24] = {-4,-3,-3,-3,-3,-3,-2,-2,-2,-2,-2,-2,-2,-1,-1,-1,-1,-1,-1,-1, 0, 0, 0, 0};
static __device__ const int d_DC[24] = { 0,-2,-1, 0, 1, 2,-3,-2,-1, 0, 1, 2, 3,-3,-2,-1, 0, 1, 2, 3,-4,-3,-2,-1};

__device__ __forceinline__ float softround_f(float x) {
    float fl = floorf(x);
    float d = x - fl - 0.5f;
    float t = __expf(d * 6.6666667f);
    float th = __fdividef(t - 1.0f, t + 1.0f);
    return fl + 0.5f + 0.53699369f * th;
}

// ---------------- 1. quantize ----------------
__global__ __launch_bounds__(256) void k_quant(
    const float* __restrict__ l0, const float* __restrict__ l1,
    const float* __restrict__ l2, const float* __restrict__ l3,
    const float* __restrict__ l4, const float* __restrict__ l5,
    const float* __restrict__ l6, float* __restrict__ ws)
{
    int t = blockIdx.x*256 + threadIdx.x;
    if (t >= NLAT) return;
    int g = 0;
    #pragma unroll
    for (int i = 1; i < 7; ++i) if (t >= d_GOFF[i]) g = i;
    int local = t - d_GOFF[g];
    const float* lp = l0;
    if      (g==1) lp=l1; else if (g==2) lp=l2; else if (g==3) lp=l3;
    else if (g==4) lp=l4; else if (g==5) lp=l5; else if (g==6) lp=l6;
    ws[d_XOFF[g] + local] = softround_f(lp[local] * 16.0f);
}

// ---------------- ARM body, v_pk_fma_f32 packed MLP ----------------
__device__ __forceinline__ void arm_body(
    const float* __restrict__ ws,
    const float* __restrict__ w0, const float* __restrict__ b0,
    const float* __restrict__ w1, const float* __restrict__ b1,
    const float* __restrict__ wo, const float* __restrict__ bo,
    float* __restrict__ out_rate, float* __restrict__ bsum, int ablk)
{
    int t = ablk*256 + threadIdx.x;
    float rate = 0.0f;
    if (t < NLAT) {
        int g = 0;
        #pragma unroll
        for (int i = 1; i < 7; ++i) if (t >= d_GOFF[i]) g = i;
        int local = t - d_GOFF[g];
        int w = d_GW[g];
        int y = (int)((unsigned)local / (unsigned)w);
        int x = local - y*w;
        const float* __restrict__ q = ws + d_XOFF[g];

        float ctx[24];
        if (y >= 4 && x >= 4 && x < w-4) {
            const float* base = q + y*w + x;
            #pragma unroll
            for (int k = 0; k < 24; ++k)
                ctx[k] = base[d_DR[k]*w + d_DC[k]];
        } else {
            #pragma unroll
            for (int k = 0; k < 24; ++k) {
                int yy = y + d_DR[k];
                int xx = x + d_DC[k];
                float v = 0.0f;
                if (yy >= 0 && (unsigned)xx < (unsigned)w) v = q[yy*w + xx];
                ctx[k] = v;
            }
        }

        const v2f* __restrict__ w0v = (const v2f*)w0;   // [24][12]
        const v2f* __restrict__ w1v = (const v2f*)w1;
        const v2f* __restrict__ b0v = (const v2f*)b0;
        const v2f* __restrict__ b1v = (const v2f*)b1;
        const v2f* __restrict__ wov = (const v2f*)wo;   // [24]
        const v2f z2 = {0.0f, 0.0f};

        v2f h0[12];
        #pragma unroll
        for (int j = 0; j < 12; ++j) h0[j] = b0v[j];
        #pragma unroll
        for (int k = 0; k < 24; ++k) {
            v2f c = {ctx[k], ctx[k]};
            #pragma unroll
            for (int j = 0; j < 12; ++j)
                h0[j] = __builtin_elementwise_fma(c, w0v[k*12+j], h0[j]);
        }
        #pragma unroll
        for (int j = 0; j < 12; ++j) h0[j] = __builtin_elementwise_max(h0[j], z2);

        v2f h1[12];
        #pragma unroll
        for (int j = 0; j < 12; ++j) h1[j] = b1v[j];
        #pragma unroll
        for (int k = 0; k < 24; ++k) {
            float hk = h0[k>>1][k&1];
            v2f c = {hk, hk};
            #pragma unroll
            for (int j = 0; j < 12; ++j)
                h1[j] = __builtin_elementwise_fma(c, w1v[k*12+j], h1[j]);
        }
        #pragma unroll
        for (int j = 0; j < 12; ++j) h1[j] = __builtin_elementwise_max(h1[j], z2);

        v2f o = {bo[0], bo[1]};
        #pragma unroll
        for (int j = 0; j < 24; ++j) {
            float hj = h1[j>>1][j&1];
            v2f hh = {hj, hj};
            o = __builtin_elementwise_fma(hh, wov[j], o);
        }

        float mu = o[0];
        float ls = fminf(fmaxf(o[1], -LSC), LSC);
        float inv_s = __expf(0.5f * ls);

        float xv = q[y*w + x];
        float a = xv + 0.5f - mu;
        float b = xv - 0.5f - mu;
        float ka = __expf(-fabsf(a) * inv_s);
        float kb = __expf(-fabsf(b) * inv_s);
        float sa = copysignf(1.0f, a);
        float sb = copysignf(1.0f, b);
        float proba = 0.5f * (sb*(kb - 1.0f) - sa*(ka - 1.0f));
        proba = fmaxf(proba, 1.52587890625e-05f);
        rate = -__log2f(proba);
        out_rate[t] = rate;
    }

    __shared__ float sm[256];
    sm[threadIdx.x] = rate;
    __syncthreads();
    #pragma unroll
    for (int st = 128; st > 0; st >>= 1) {
        if (threadIdx.x < st) sm[threadIdx.x] += sm[threadIdx.x + st];
        __syncthreads();
    }
    if (threadIdx.x == 0) bsum[ablk] = sm[0];
}

// ---------------- fused level: pre(7x7 SAME) + convT8x8s2 + crop, LDS-staged ----
template<int CH,int H,int W,int HT,int WT>
__global__ __launch_bounds__(256) void k_level(
    const float* __restrict__ src, float* __restrict__ dst,
    const float* __restrict__ k7, const float* __restrict__ k8,
    const float* __restrict__ ws,
    const float* __restrict__ w0, const float* __restrict__ b0,
    const float* __restrict__ w1, const float* __restrict__ b1,
    const float* __restrict__ wo, const float* __restrict__ bo,
    float* __restrict__ out_rate, float* __restrict__ bsum,
    int arm_off, int arm_cnt)
{
    if ((int)blockIdx.x < arm_cnt) {
        arm_body(ws, w0, b0, w1, b1, wo, bo, out_rate, bsum, arm_off + blockIdx.x);
        return;
    }
    constexpr int HB=(HT+1)/2, WB=(WT+1)/2;
    constexpr int TBH=(HB+15)/16, TBW=(WB+15)/16;
    int blk = blockIdx.x - arm_cnt;
    int c   = blk / (TBH*TBW);
    int r2  = blk - c*(TBH*TBW);
    int tpy = r2 / TBW, tpx = r2 - (r2/TBW)*TBW;
    int IR0 = tpy*16 - 5, IC0 = tpx*16 - 5;   // input tile origin (26x26)

    __shared__ float in_t[26*26];
    __shared__ float pre_t[20*24];   // stride 24

    const float* __restrict__ sc = src + c*H*W;
    for (int i = threadIdx.x; i < 676; i += 256) {
        int r = i/26, col = i - (i/26)*26;
        int gy = IR0 + r, gx = IC0 + col;
        in_t[i] = (gy >= 0 && gy < H && gx >= 0 && gx < W) ? sc[gy*W + gx] : 0.0f;
    }
    __syncthreads();

    for (int i = threadIdx.x; i < 400; i += 256) {
        int r = i/20, s = i - (i/20)*20;
        int gy = IR0 + 3 + r, gx = IC0 + 3 + s;
        float acc = 0.0f;
        if (gy >= 0 && gy < H && gx >= 0 && gx < W) {
            #pragma unroll
            for (int a = 0; a < 7; ++a)
                #pragma unroll
                for (int b = 0; b < 7; ++b)
                    acc = fmaf(in_t[(r+a)*26 + (s+b)], k7[a*7+b], acc);
        }
        pre_t[r*24 + s] = acc;
    }
    __syncthreads();

    int ty = threadIdx.x >> 4, tx = threadIdx.x & 15;
    int pb = tpy*16 + ty, qb = tpx*16 + tx;
    if (pb >= HB || qb >= WB) return;
    float* __restrict__ dc = dst + (c+1)*HT*WT;
    #pragma unroll
    for (int pp = 0; pp < 2; ++pp) {
        int p = 2*pb + pp;
        if (p >= HT) break;
        #pragma unroll
        for (int qq = 0; qq < 2; ++qq) {
            int q = 2*qb + qq;
            if (q >= WT) continue;
            float acc = 0.0f;
            #pragma unroll
            for (int t = 0; t < 4; ++t)
                #pragma unroll
                for (int u = 0; u < 4; ++u)
                    acc = fmaf(pre_t[(ty+pp+t)*24 + (tx+qq+u)], k8[(pp+2*t)*8 + (qq+2*u)], acc);
            dc[p*WT + q] = acc;
        }
    }
}

// ---------------- last level fused with syn01, pk-fma MLP, 16x32 tiles --------
// grid = 45 x 40 tiles of 16(rows)x32(cols) output px; base tile 8x16 of lvl1.
// thread = (pp, ty, tx): 2 horizontally-adjacent output px, v2f-packed MLP.
__global__ __launch_bounds__(256, 4) void k_lvl6syn(
    const float* __restrict__ src,      // lvl1 buffer: 6 ch of 360x640
    const float* __restrict__ ch0,      // ws+0: quantized latent0 720x1280
    const float* __restrict__ k7, const float* __restrict__ k8,
    const float* __restrict__ w0, const float* __restrict__ b0,
    const float* __restrict__ w1, const float* __restrict__ b1,
    float* __restrict__ s1,
    const float* __restrict__ bsum, float* __restrict__ out_bpd)
{
    constexpr int H=360, W=640;
    if (blockIdx.x == 0) {
        __shared__ float smr[256];
        float s = 0.0f;
        for (int i = threadIdx.x; i < NB_ARM; i += 256) s += bsum[i];
        smr[threadIdx.x] = s;
        __syncthreads();
        #pragma unroll
        for (int st = 128; st > 0; st >>= 1) {
            if (threadIdx.x < st) smr[threadIdx.x] += smr[threadIdx.x + st];
            __syncthreads();
        }
        if (threadIdx.x == 0) out_bpd[0] = smr[0] * (1.0f/2764800.0f);
        __syncthreads();
    }
    int tpy = blockIdx.x / 40, tpx = blockIdx.x - (blockIdx.x/40)*40;  // 45 x 40
    int IR0 = tpy*8 - 5, IC0 = tpx*16 - 5;   // halo origin; 18 rows x 26 cols

    __shared__ float in_t[6][18*26];   // 468
    __shared__ float pre_t[6][12*24];  // 12 rows x stride 24 (cols 0..19 used)

    for (int i = threadIdx.x; i < 6*468; i += 256) {
        int c = i / 468, r2 = i - c*468;
        int r = r2/26, col = r2 - r*26;
        int gy = IR0 + r, gx = IC0 + col;
        in_t[c][r2] = (gy >= 0 && gy < H && gx >= 0 && gx < W) ? src[c*H*W + gy*W + gx] : 0.0f;
    }
    __syncthreads();

    for (int i = threadIdx.x; i < 6*240; i += 256) {
        int c = i/240, r2 = i - c*240;
        int r = r2/20, s = r2 - r*20;
        int gy = IR0 + 3 + r, gx = IC0 + 3 + s;
        float acc = 0.0f;
        if (gy >= 0 && gy < H && gx >= 0 && gx < W) {
            #pragma unroll
            for (int a = 0; a < 7; ++a)
                #pragma unroll
                for (int b = 0; b < 7; ++b)
                    acc = fmaf(in_t[c][(r+a)*26 + (s+b)], k7[a*7+b], acc);
        }
        pre_t[c][r*24 + s] = acc;
    }
    __syncthreads();

    int tx = threadIdx.x & 15;
    int ty = (threadIdx.x >> 4) & 7;
    int pp = threadIdx.x >> 7;          // 0 or 1
    int pb = tpy*8 + ty, qb = tpx*16 + tx;   // always in-bounds (45*8=360, 40*16=640)

    // in2[c] = packed {qq=0, qq=1} inputs; c0 = ch0 pixel pair, c1..6 = ups channels
    v2f in2[7];
    #pragma unroll
    for (int c = 0; c < 6; ++c) {
        v2f acc = {0.0f, 0.0f};
        #pragma unroll
        for (int qq = 0; qq < 2; ++qq) {
            float a = 0.0f;
            #pragma unroll
            for (int t = 0; t < 4; ++t)
                #pragma unroll
                for (int uu = 0; uu < 4; ++uu)
                    a = fmaf(pre_t[c][(ty+pp+t)*24 + (tx+qq+uu)], k8[(pp+2*t)*8 + (qq+2*uu)], a);
            acc[qq] = a;
        }
        in2[c+1] = acc;
    }

    int pix00 = (2*pb + pp)*1280 + 2*qb;
    in2[0] = *(const v2f*)&ch0[pix00];

    v2f out2[6];
    #pragma unroll
    for (int j = 0; j < 6; ++j) out2[j] = (v2f){b1[j], b1[j]};

    const v2f z2 = {0.0f, 0.0f};
    for (int o = 0; o < 48; ++o) {
        float b0o = b0[o];
        v2f a2 = {b0o, b0o};
        #pragma unroll
        for (int c = 0; c < 7; ++c) {
            float wc = w0[o*7 + c];
            a2 = __builtin_elementwise_fma(in2[c], (v2f){wc, wc}, a2);
        }
        a2 = __builtin_elementwise_max(a2, z2);
        #pragma unroll
        for (int j = 0; j < 6; ++j) {
            float wj = w1[j*48 + o];
            out2[j] = __builtin_elementwise_fma(a2, (v2f){wj, wj}, out2[j]);
        }
    }

    #pragma unroll
    for (int j = 0; j < 6; ++j)
        *(v2f*)&s1[j*921600 + pix00] = out2[j];
}

// ---------------- 4b. s2 = relu(conv3x3(s1)+b2 + s1)  (validated R4) ---------
__global__ __launch_bounds__(256) void k_s2(
    const float* __restrict__ s1,
    const float* __restrict__ w2, const float* __restrict__ b2,
    float* __restrict__ s2)
{
    int x = blockIdx.x*256 + threadIdx.x;
    int y = blockIdx.y;
    int pix = y*1280 + x;
    float acc[6];
    #pragma unroll
    for (int o = 0; o < 6; ++o) acc[o] = b2[o];
    if (x >= 1 && x < 1279 && y >= 1 && y < 719) {
        #pragma unroll
        for (int ci = 0; ci < 6; ++ci) {
            const float* p = s1 + ci*921600 + pix;
            #pragma unroll
            for (int dy = 0; dy < 3; ++dy)
                #pragma unroll
                for (int dx = 0; dx < 3; ++dx) {
                    float v = p[(dy-1)*1280 + dx - 1];
                    #pragma unroll
                    for (int o = 0; o < 6; ++o)
                        acc[o] = fmaf(v, w2[(o*6 + ci)*9 + dy*3 + dx], acc[o]);
                }
        }
    } else {
        #pragma unroll
        for (int ci = 0; ci < 6; ++ci) {
            const float* p = s1 + ci*921600;
            #pragma unroll
            for (int dy = 0; dy < 3; ++dy) {
                int yy = y + dy - 1;
                if (yy < 0 || yy >= 720) continue;
                #pragma unroll
                for (int dx = 0; dx < 3; ++dx) {
                    int xx = x + dx - 1;
                    if (xx < 0 || xx >= 1280) continue;
                    float v = p[yy*1280 + xx];
                    #pragma unroll
                    for (int o = 0; o < 6; ++o)
                        acc[o] = fmaf(v, w2[(o*6 + ci)*9 + dy*3 + dx], acc[o]);
                }
            }
        }
    }
    #pragma unroll
    for (int o = 0; o < 6; ++o)
        s2[o*921600 + pix] = fmaxf(acc[o] + s1[o*921600 + pix], 0.0f);
}

// ---------------- 4c. s3 = conv3x3(s2)+b3 + s2 ; emit mu / scale (validated R4)
__global__ __launch_bounds__(256) void k_s3(
    const float* __restrict__ s2,
    const float* __restrict__ w3, const float* __restrict__ b3,
    float* __restrict__ out)
{
    int x = blockIdx.x*256 + threadIdx.x;
    int y = blockIdx.y;
    int pix = y*1280 + x;
    float acc[6];
    #pragma unroll
    for (int o = 0; o < 6; ++o) acc[o] = b3[o];
    if (x >= 1 && x < 1279 && y >= 1 && y < 719) {
        #pragma unroll
        for (int ci = 0; ci < 6; ++ci) {
            const float* p = s2 + ci*921600 + pix;
            #pragma unroll
            for (int dy = 0; dy < 3; ++dy)
                #pragma unroll
                for (int dx = 0; dx < 3; ++dx) {
                    float v = p[(dy-1)*1280 + dx - 1];
                    #pragma unroll
                    for (int o = 0; o < 6; ++o)
                        acc[o] = fmaf(v, w3[(o*6 + ci)*9 + dy*3 + dx], acc[o]);
                }
        }
    } else {
        #pragma unroll
        for (int ci = 0; ci < 6; ++ci) {
            const float* p = s2 + ci*921600;
            #pragma unroll
            for (int dy = 0; dy < 3; ++dy) {
                int yy = y + dy - 1;
                if (yy < 0 || yy >= 720) continue;
                #pragma unroll
                for (int dx = 0; dx < 3; ++dx) {
                    int xx = x + dx - 1;
                    if (xx < 0 || xx >= 1280) continue;
                    float v = p[yy*1280 + xx];
                    #pragma unroll
                    for (int o = 0; o < 6; ++o)
                        acc[o] = fmaf(v, w3[(o*6 + ci)*9 + dy*3 + dx], acc[o]);
                }
            }
        }
    }
    #pragma unroll
    for (int o = 0; o < 6; ++o) {
        float v = acc[o] + s2[o*921600 + pix];
        if (o < 3) {
            out[o*921600 + pix] = v;
        } else {
            float ls = fminf(fmaxf(v, -LSC), LSC);
            out[2764800 + (o-3)*921600 + pix] = __expf(-0.5f * ls);
        }
    }
}

// ---------------- host ----------------
extern "C" void kernel_launch(void* const* d_in, const int* in_sizes, int n_in,
                              void* d_out, int out_size, void* d_ws, size_t ws_size,
                              hipStream_t stream)
{
    const float* lat[7];
    for (int i = 0; i < 7; ++i) lat[i] = (const float*)d_in[i];
    const float* arm_w0  = (const float*)d_in[7];
    const float* arm_b0  = (const float*)d_in[8];
    const float* arm_w1  = (const float*)d_in[9];
    const float* arm_b1  = (const float*)d_in[10];
    const float* arm_wo  = (const float*)d_in[11];
    const float* arm_bo  = (const float*)d_in[12];
    const float* pre_k   = (const float*)d_in[13];
    const float* ups_k   = (const float*)d_in[14];
    const float* syn_w0  = (const float*)d_in[15];
    const float* syn_b0  = (const float*)d_in[16];
    const float* syn_w1  = (const float*)d_in[17];
    const float* syn_b1  = (const float*)d_in[18];
    const float* syn_w2  = (const float*)d_in[19];
    const float* syn_b2  = (const float*)d_in[20];
    const float* syn_w3  = (const float*)d_in[21];
    const float* syn_b3  = (const float*)d_in[22];

    float* out = (float*)d_out;
    float* ws  = (float*)d_ws;
    float* rate = out + RATE_OFF;
    float* bsum = ws + BSUM_OFF;

    k_quant<<<dim3(NB_ARM), dim3(256), 0, stream>>>(
        lat[0],lat[1],lat[2],lat[3],lat[4],lat[5],lat[6], ws);

    #define ARM_ARGS ws, arm_w0, arm_b0, arm_w1, arm_b1, arm_wo, arm_bo, rate, bsum
    k_level<1,12,20,23,40><<<dim3(1100+2),   dim3(256), 0, stream>>>(
        ws+8191840, ws+8190000, pre_k+0*49, ups_k+0*64, ARM_ARGS, 0, 1100);
    k_level<2,23,40,45,80><<<dim3(1100+12),  dim3(256), 0, stream>>>(
        ws+8190000, ws+8179200, pre_k+1*49, ups_k+1*64, ARM_ARGS, 1100, 1100);
    k_level<3,45,80,90,160><<<dim3(1100+45), dim3(256), 0, stream>>>(
        ws+8179200, ws+8121600, pre_k+2*49, ups_k+2*64, ARM_ARGS, 2200, 1100);
    k_level<4,90,160,180,320><<<dim3(1100+240), dim3(256), 0, stream>>>(
        ws+8121600, ws+7833600, pre_k+3*49, ups_k+3*64, ARM_ARGS, 3300, 1100);
    k_level<5,180,320,360,640><<<dim3(400+1200), dim3(256), 0, stream>>>(
        ws+7833600, ws+6451200, pre_k+4*49, ups_k+4*64, ARM_ARGS, 4400, 400);
    #undef ARM_ARGS

    // s=5 fused with syn01 (+bpd reduce in block 0): 45x40 = 1800 tiles of 16x32
    k_lvl6syn<<<dim3(1800), dim3(256), 0, stream>>>(
        ws+6451200, ws+0, pre_k+5*49, ups_k+5*64,
        syn_w0, syn_b0, syn_w1, syn_b1, ws + S1_OFF,
        bsum, out + BPD_OFF);

    // separate s2 / s3 (validated R4 path: uniform weights -> scalar loads)
    k_s2<<<dim3(5, 720), dim3(256), 0, stream>>>(
        ws + S1_OFF, syn_w2, syn_b2, ws + 0);
    k_s3<<<dim3(5, 720), dim3(256), 0, stream>>>(
        ws + 0, syn_w3, syn_b3, out);
}

// Round 9
// 237.790 us; speedup vs baseline: 1.2598x; 1.2598x over previous
//
#include <hip/hip_runtime.h>

// ---------------- problem constants ----------------
#define NLAT 1228760
#define RATE_OFF 5529600      // 2*3*921600
#define BPD_OFF 6758360
#define NB_ARM 4800           // ceil(NLAT/256)
#define LSC 13.8155f

typedef float v2f __attribute__((ext_vector_type(2)));

// grid sizes: (720,1280)(360,640)(180,320)(90,160)(45,80)(23,40)(12,20)
static __device__ const int d_GOFF[8] = {0,921600,1152000,1209600,1224000,1227600,1228520,1228760};
static __device__ const int d_GW[7]   = {1280,640,320,160,80,40,20};
static __device__ const int d_XOFF[7] = {0,6451200,7833600,8121600,8179200,8190000,8191840};

#define S1_OFF   9574480   // 6*921600
#define BSUM_OFF 15104080  // NB_ARM partial sums

// 24 causal context offsets
static __device__ const int d_DR[24] = {-4,-3,-3,-3,-3,-3,-2,-2,-2,-2,-2,-2,-2,-1,-1,-1,-1,-1,-1,-1, 0, 0, 0, 0};
static __device__ const int d_DC[24] = { 0,-2,-1, 0, 1, 2,-3,-2,-1, 0, 1, 2, 3,-3,-2,-1, 0, 1, 2, 3,-4,-3,-2,-1};

__device__ __forceinline__ float softround_f(float x) {
    float fl = floorf(x);
    float d = x - fl - 0.5f;
    float t = __expf(d * 6.6666667f);
    float th = __fdividef(t - 1.0f, t + 1.0f);
    return fl + 0.5f + 0.53699369f * th;
}

// ---------------- 1. quantize ----------------
__global__ __launch_bounds__(256) void k_quant(
    const float* __restrict__ l0, const float* __restrict__ l1,
    const float* __restrict__ l2, const float* __restrict__ l3,
    const float* __restrict__ l4, const float* __restrict__ l5,
    const float* __restrict__ l6, float* __restrict__ ws)
{
    int t = blockIdx.x*256 + threadIdx.x;
    if (t >= NLAT) return;
    int g = 0;
    #pragma unroll
    for (int i = 1; i < 7; ++i) if (t >= d_GOFF[i]) g = i;
    int local = t - d_GOFF[g];
    const float* lp = l0;
    if      (g==1) lp=l1; else if (g==2) lp=l2; else if (g==3) lp=l3;
    else if (g==4) lp=l4; else if (g==5) lp=l5; else if (g==6) lp=l6;
    ws[d_XOFF[g] + local] = softround_f(lp[local] * 16.0f);
}

// ---------------- ARM body, v_pk_fma_f32 packed MLP ----------------
__device__ __forceinline__ void arm_body(
    const float* __restrict__ ws,
    const float* __restrict__ w0, const float* __restrict__ b0,
    const float* __restrict__ w1, const float* __restrict__ b1,
    const float* __restrict__ wo, const float* __restrict__ bo,
    float* __restrict__ out_rate, float* __restrict__ bsum, int ablk)
{
    int t = ablk*256 + threadIdx.x;
    float rate = 0.0f;
    if (t < NLAT) {
        int g = 0;
        #pragma unroll
        for (int i = 1; i < 7; ++i) if (t >= d_GOFF[i]) g = i;
        int local = t - d_GOFF[g];
        int w = d_GW[g];
        int y = (int)((unsigned)local / (unsigned)w);
        int x = local - y*w;
        const float* __restrict__ q = ws + d_XOFF[g];

        float ctx[24];
        if (y >= 4 && x >= 4 && x < w-4) {
            const float* base = q + y*w + x;
            #pragma unroll
            for (int k = 0; k < 24; ++k)
                ctx[k] = base[d_DR[k]*w + d_DC[k]];
        } else {
            #pragma unroll
            for (int k = 0; k < 24; ++k) {
                int yy = y + d_DR[k];
                int xx = x + d_DC[k];
                float v = 0.0f;
                if (yy >= 0 && (unsigned)xx < (unsigned)w) v = q[yy*w + xx];
                ctx[k] = v;
            }
        }

        const v2f* __restrict__ w0v = (const v2f*)w0;   // [24][12]
        const v2f* __restrict__ w1v = (const v2f*)w1;
        const v2f* __restrict__ b0v = (const v2f*)b0;
        const v2f* __restrict__ b1v = (const v2f*)b1;
        const v2f* __restrict__ wov = (const v2f*)wo;   // [24]
        const v2f z2 = {0.0f, 0.0f};

        v2f h0[12];
        #pragma unroll
        for (int j = 0; j < 12; ++j) h0[j] = b0v[j];
        #pragma unroll
        for (int k = 0; k < 24; ++k) {
            v2f c = {ctx[k], ctx[k]};
            #pragma unroll
            for (int j = 0; j < 12; ++j)
                h0[j] = __builtin_elementwise_fma(c, w0v[k*12+j], h0[j]);
        }
        #pragma unroll
        for (int j = 0; j < 12; ++j) h0[j] = __builtin_elementwise_max(h0[j], z2);

        v2f h1[12];
        #pragma unroll
        for (int j = 0; j < 12; ++j) h1[j] = b1v[j];
        #pragma unroll
        for (int k = 0; k < 24; ++k) {
            float hk = h0[k>>1][k&1];
            v2f c = {hk, hk};
            #pragma unroll
            for (int j = 0; j < 12; ++j)
                h1[j] = __builtin_elementwise_fma(c, w1v[k*12+j], h1[j]);
        }
        #pragma unroll
        for (int j = 0; j < 12; ++j) h1[j] = __builtin_elementwise_max(h1[j], z2);

        v2f o = {bo[0], bo[1]};
        #pragma unroll
        for (int j = 0; j < 24; ++j) {
            float hj = h1[j>>1][j&1];
            v2f hh = {hj, hj};
            o = __builtin_elementwise_fma(hh, wov[j], o);
        }

        float mu = o[0];
        float ls = fminf(fmaxf(o[1], -LSC), LSC);
        float inv_s = __expf(0.5f * ls);

        float xv = q[y*w + x];
        float a = xv + 0.5f - mu;
        float b = xv - 0.5f - mu;
        float ka = __expf(-fabsf(a) * inv_s);
        float kb = __expf(-fabsf(b) * inv_s);
        float sa = copysignf(1.0f, a);
        float sb = copysignf(1.0f, b);
        float proba = 0.5f * (sb*(kb - 1.0f) - sa*(ka - 1.0f));
        proba = fmaxf(proba, 1.52587890625e-05f);
        rate = -__log2f(proba);
        out_rate[t] = rate;
    }

    __shared__ float sm[256];
    sm[threadIdx.x] = rate;
    __syncthreads();
    #pragma unroll
    for (int st = 128; st > 0; st >>= 1) {
        if (threadIdx.x < st) sm[threadIdx.x] += sm[threadIdx.x + st];
        __syncthreads();
    }
    if (threadIdx.x == 0) bsum[ablk] = sm[0];
}

// ---------------- fused level: pre(7x7 SAME) + convT8x8s2 + crop, LDS-staged ----
template<int CH,int H,int W,int HT,int WT>
__global__ __launch_bounds__(256) void k_level(
    const float* __restrict__ src, float* __restrict__ dst,
    const float* __restrict__ k7, const float* __restrict__ k8,
    const float* __restrict__ ws,
    const float* __restrict__ w0, const float* __restrict__ b0,
    const float* __restrict__ w1, const float* __restrict__ b1,
    const float* __restrict__ wo, const float* __restrict__ bo,
    float* __restrict__ out_rate, float* __restrict__ bsum,
    int arm_off, int arm_cnt)
{
    if ((int)blockIdx.x < arm_cnt) {
        arm_body(ws, w0, b0, w1, b1, wo, bo, out_rate, bsum, arm_off + blockIdx.x);
        return;
    }
    constexpr int HB=(HT+1)/2, WB=(WT+1)/2;
    constexpr int TBH=(HB+15)/16, TBW=(WB+15)/16;
    int blk = blockIdx.x - arm_cnt;
    int c   = blk / (TBH*TBW);
    int r2  = blk - c*(TBH*TBW);
    int tpy = r2 / TBW, tpx = r2 - (r2/TBW)*TBW;
    int IR0 = tpy*16 - 5, IC0 = tpx*16 - 5;   // input tile origin (26x26)

    __shared__ float in_t[26*26];
    __shared__ float pre_t[20*24];   // stride 24

    const float* __restrict__ sc = src + c*H*W;
    for (int i = threadIdx.x; i < 676; i += 256) {
        int r = i/26, col = i - (i/26)*26;
        int gy = IR0 + r, gx = IC0 + col;
        in_t[i] = (gy >= 0 && gy < H && gx >= 0 && gx < W) ? sc[gy*W + gx] : 0.0f;
    }
    __syncthreads();

    for (int i = threadIdx.x; i < 400; i += 256) {
        int r = i/20, s = i - (i/20)*20;
        int gy = IR0 + 3 + r, gx = IC0 + 3 + s;
        float acc = 0.0f;
        if (gy >= 0 && gy < H && gx >= 0 && gx < W) {
            #pragma unroll
            for (int a = 0; a < 7; ++a)
                #pragma unroll
                for (int b = 0; b < 7; ++b)
                    acc = fmaf(in_t[(r+a)*26 + (s+b)], k7[a*7+b], acc);
        }
        pre_t[r*24 + s] = acc;
    }
    __syncthreads();

    int ty = threadIdx.x >> 4, tx = threadIdx.x & 15;
    int pb = tpy*16 + ty, qb = tpx*16 + tx;
    if (pb >= HB || qb >= WB) return;
    float* __restrict__ dc = dst + (c+1)*HT*WT;
    #pragma unroll
    for (int pp = 0; pp < 2; ++pp) {
        int p = 2*pb + pp;
        if (p >= HT) break;
        #pragma unroll
        for (int qq = 0; qq < 2; ++qq) {
            int q = 2*qb + qq;
            if (q >= WT) continue;
            float acc = 0.0f;
            #pragma unroll
            for (int t = 0; t < 4; ++t)
                #pragma unroll
                for (int u = 0; u < 4; ++u)
                    acc = fmaf(pre_t[(ty+pp+t)*24 + (tx+qq+u)], k8[(pp+2*t)*8 + (qq+2*u)], acc);
            dc[p*WT + q] = acc;
        }
    }
}

// ---------------- fused levels s=0 + s=1: lvl6 -> lvl5 ch1 (recomputed in-block)
// -> lvl4 ch1,ch2.  12 tile blocks; lvl5 ch1 never touches global memory.
__global__ __launch_bounds__(256) void k_level01(
    const float* __restrict__ src5,     // lvl5 ch0 (quant latent5), 23x40
    const float* __restrict__ src6,     // lvl6 ch0 (quant latent6), 12x20
    float* __restrict__ dst,            // lvl4 base (45x80 per ch)
    const float* __restrict__ k7_0, const float* __restrict__ k8_0,
    const float* __restrict__ k7_1, const float* __restrict__ k8_1,
    const float* __restrict__ ws,
    const float* __restrict__ w0, const float* __restrict__ b0,
    const float* __restrict__ w1, const float* __restrict__ b1,
    const float* __restrict__ wo, const float* __restrict__ bo,
    float* __restrict__ out_rate, float* __restrict__ bsum,
    int arm_off, int arm_cnt)
{
    if ((int)blockIdx.x < arm_cnt) {
        arm_body(ws, w0, b0, w1, b1, wo, bo, out_rate, bsum, arm_off + blockIdx.x);
        return;
    }
    // s=1 geometry: in lvl5 23x40 (2ch), out lvl4 45x80; HB=23,WB=40,TBH=2,TBW=3
    int blk = blockIdx.x - arm_cnt;        // 0..11
    int c   = blk / 6;                     // input channel 0/1
    int r2  = blk - c*6;
    int tpy = r2 / 3, tpx = r2 - (r2/3)*3;
    int IR0 = tpy*16 - 5, IC0 = tpx*16 - 5;

    __shared__ float lat6[240];        // 12x20
    __shared__ float pre0_t[240];      // 12x20
    __shared__ float in_t[26*26];
    __shared__ float pre_t[20*24];

    // stage -1: whole lvl6 into LDS (cheap; done by all 12 blocks)
    for (int i = threadIdx.x; i < 240; i += 256) lat6[i] = src6[i];
    __syncthreads();
    // stage 0: pre0 = 7x7 SAME conv over full 12x20
    for (int i = threadIdx.x; i < 240; i += 256) {
        int r = i/20, s = i - (i/20)*20;
        float acc = 0.0f;
        #pragma unroll
        for (int a = 0; a < 7; ++a) {
            int rr = r + a - 3;
            if (rr < 0 || rr >= 12) continue;
            #pragma unroll
            for (int b = 0; b < 7; ++b) {
                int ss = s + b - 3;
                if (ss < 0 || ss >= 20) continue;
                acc = fmaf(lat6[rr*20 + ss], k7_0[a*7+b], acc);
            }
        }
        pre0_t[i] = acc;
    }
    __syncthreads();

    // stage 1: in_t 26x26 region of lvl5 channel c
    for (int i = threadIdx.x; i < 676; i += 256) {
        int r = i/26, col = i - (i/26)*26;
        int p = IR0 + r, q = IC0 + col;
        float v = 0.0f;
        if (p >= 0 && p < 23 && q >= 0 && q < 40) {
            if (c == 0) {
                v = src5[p*40 + q];
            } else {
                int pp = p & 1, qq2 = q & 1;
                float acc = 0.0f;
                #pragma unroll
                for (int t = 0; t < 4; ++t) {
                    int a = pp + 2*t;
                    int i6 = (p + a - 4) / 2;
                    if (i6 < 0 || i6 >= 12) continue;
                    #pragma unroll
                    for (int u = 0; u < 4; ++u) {
                        int b = qq2 + 2*u;
                        int j6 = (q + b - 4) / 2;
                        if (j6 < 0 || j6 >= 20) continue;
                        acc = fmaf(pre0_t[i6*20 + j6], k8_0[a*8 + b], acc);
                    }
                }
                v = acc;
            }
        }
        in_t[i] = v;
    }
    __syncthreads();

    // stage 2: pre1 on 20x20 window
    for (int i = threadIdx.x; i < 400; i += 256) {
        int r = i/20, s = i - (i/20)*20;
        int gy = IR0 + 3 + r, gx = IC0 + 3 + s;
        float acc = 0.0f;
        if (gy >= 0 && gy < 23 && gx >= 0 && gx < 40) {
            #pragma unroll
            for (int a = 0; a < 7; ++a)
                #pragma unroll
                for (int b = 0; b < 7; ++b)
                    acc = fmaf(in_t[(r+a)*26 + (s+b)], k7_1[a*7+b], acc);
        }
        pre_t[r*24 + s] = acc;
    }
    __syncthreads();

    // stage 3: ups -> lvl4 channel c+1
    int ty = threadIdx.x >> 4, tx = threadIdx.x & 15;
    int pb = tpy*16 + ty, qb = tpx*16 + tx;
    if (pb >= 23 || qb >= 40) return;
    float* __restrict__ dc = dst + (c+1)*45*80;
    #pragma unroll
    for (int pp = 0; pp < 2; ++pp) {
        int p = 2*pb + pp;
        if (p >= 45) break;
        #pragma unroll
        for (int qq = 0; qq < 2; ++qq) {
            int q = 2*qb + qq;
            if (q >= 80) continue;
            float acc = 0.0f;
            #pragma unroll
            for (int t = 0; t < 4; ++t)
                #pragma unroll
                for (int u = 0; u < 4; ++u)
                    acc = fmaf(pre_t[(ty+pp+t)*24 + (tx+qq+u)], k8_1[(pp+2*t)*8 + (qq+2*u)], acc);
            dc[p*80 + q] = acc;
        }
    }
}

// ---------------- last level fused with syn01, pk-fma MLP, 16x32 tiles --------
__global__ __launch_bounds__(256, 4) void k_lvl6syn(
    const float* __restrict__ src,      // lvl1 buffer: 6 ch of 360x640
    const float* __restrict__ ch0,      // ws+0: quantized latent0 720x1280
    const float* __restrict__ k7, const float* __restrict__ k8,
    const float* __restrict__ w0, const float* __restrict__ b0,
    const float* __restrict__ w1, const float* __restrict__ b1,
    float* __restrict__ s1,
    const float* __restrict__ bsum, float* __restrict__ out_bpd)
{
    constexpr int H=360, W=640;
    if (blockIdx.x == 0) {
        __shared__ float smr[256];
        float s = 0.0f;
        for (int i = threadIdx.x; i < NB_ARM; i += 256) s += bsum[i];
        smr[threadIdx.x] = s;
        __syncthreads();
        #pragma unroll
        for (int st = 128; st > 0; st >>= 1) {
            if (threadIdx.x < st) smr[threadIdx.x] += smr[threadIdx.x + st];
            __syncthreads();
        }
        if (threadIdx.x == 0) out_bpd[0] = smr[0] * (1.0f/2764800.0f);
        __syncthreads();
    }
    int tpy = blockIdx.x / 40, tpx = blockIdx.x - (blockIdx.x/40)*40;  // 45 x 40
    int IR0 = tpy*8 - 5, IC0 = tpx*16 - 5;   // halo origin; 18 rows x 26 cols

    __shared__ float in_t[6][18*26];   // 468
    __shared__ float pre_t[6][12*24];  // 12 rows x stride 24 (cols 0..19 used)

    for (int i = threadIdx.x; i < 6*468; i += 256) {
        int c = i / 468, r2 = i - c*468;
        int r = r2/26, col = r2 - r*26;
        int gy = IR0 + r, gx = IC0 + col;
        in_t[c][r2] = (gy >= 0 && gy < H && gx >= 0 && gx < W) ? src[c*H*W + gy*W + gx] : 0.0f;
    }
    __syncthreads();

    for (int i = threadIdx.x; i < 6*240; i += 256) {
        int c = i/240, r2 = i - c*240;
        int r = r2/20, s = r2 - r*20;
        int gy = IR0 + 3 + r, gx = IC0 + 3 + s;
        float acc = 0.0f;
        if (gy >= 0 && gy < H && gx >= 0 && gx < W) {
            #pragma unroll
            for (int a = 0; a < 7; ++a)
                #pragma unroll
                for (int b = 0; b < 7; ++b)
                    acc = fmaf(in_t[c][(r+a)*26 + (s+b)], k7[a*7+b], acc);
        }
        pre_t[c][r*24 + s] = acc;
    }
    __syncthreads();

    int tx = threadIdx.x & 15;
    int ty = (threadIdx.x >> 4) & 7;
    int pp = threadIdx.x >> 7;          // 0 or 1
    int pb = tpy*8 + ty, qb = tpx*16 + tx;

    v2f in2[7];
    #pragma unroll
    for (int c = 0; c < 6; ++c) {
        v2f acc = {0.0f, 0.0f};
        #pragma unroll
        for (int qq = 0; qq < 2; ++qq) {
            float a = 0.0f;
            #pragma unroll
            for (int t = 0; t < 4; ++t)
                #pragma unroll
                for (int uu = 0; uu < 4; ++uu)
                    a = fmaf(pre_t[c][(ty+pp+t)*24 + (tx+qq+uu)], k8[(pp+2*t)*8 + (qq+2*uu)], a);
            acc[qq] = a;
        }
        in2[c+1] = acc;
    }

    int pix00 = (2*pb + pp)*1280 + 2*qb;
    in2[0] = *(const v2f*)&ch0[pix00];

    v2f out2[6];
    #pragma unroll
    for (int j = 0; j < 6; ++j) out2[j] = (v2f){b1[j], b1[j]};

    const v2f z2 = {0.0f, 0.0f};
    for (int o = 0; o < 48; ++o) {
        float b0o = b0[o];
        v2f a2 = {b0o, b0o};
        #pragma unroll
        for (int c = 0; c < 7; ++c) {
            float wc = w0[o*7 + c];
            a2 = __builtin_elementwise_fma(in2[c], (v2f){wc, wc}, a2);
        }
        a2 = __builtin_elementwise_max(a2, z2);
        #pragma unroll
        for (int j = 0; j < 6; ++j) {
            float wj = w1[j*48 + o];
            out2[j] = __builtin_elementwise_fma(a2, (v2f){wj, wj}, out2[j]);
        }
    }

    #pragma unroll
    for (int j = 0; j < 6; ++j)
        *(v2f*)&s1[j*921600 + pix00] = out2[j];
}

// ---------------- fused s2+s3, uniform weights, LDS staged, 16x32 tiles -------
// stage0: s1 halo (20x36, zero outside image) -> LDS; stageA: s2 halo (18x34)
// per-pixel all-6-ch accumulators (compile-time weight idx => s_load); stageB:
// s3 v2f-packed over px pairs -> out (mu/scale).
__global__ __launch_bounds__(256, 4) void k_s2s3(
    const float* __restrict__ s1,
    const float* __restrict__ w2, const float* __restrict__ b2,
    const float* __restrict__ w3, const float* __restrict__ b3,
    float* __restrict__ out)
{
    int tpy = blockIdx.x / 40, tpx = blockIdx.x - (blockIdx.x/40)*40;  // 45 x 40
    int R0 = tpy*16, C0 = tpx*32;

    __shared__ float s1t[6][20*36];   // rows R0-2..R0+17, cols C0-2..C0+33
    __shared__ float s2t[6][18*36];   // rows R0-1..R0+16, cols C0-1..C0+32 (34 used)

    for (int i = threadIdx.x; i < 6*720; i += 256) {
        int c = i/720, r2 = i - c*720;
        int r = r2/36, col = r2 - r*36;
        int gy = R0 - 2 + r, gx = C0 - 2 + col;
        s1t[c][r2] = (gy >= 0 && gy < 720 && gx >= 0 && gx < 1280)
                   ? s1[c*921600 + gy*1280 + gx] : 0.0f;
    }
    __syncthreads();

    // stage A: s2 on 18x34 halo (zeros in s1t handle SAME padding; no tap checks)
    for (int i = threadIdx.x; i < 612; i += 256) {
        int r = i/34, col = i - (i/34)*34;
        int gy = R0 - 1 + r, gx = C0 - 1 + col;
        if (gy >= 0 && gy < 720 && gx >= 0 && gx < 1280) {
            float acc[6];
            #pragma unroll
            for (int o = 0; o < 6; ++o) acc[o] = b2[o];
            #pragma unroll
            for (int ci = 0; ci < 6; ++ci)
                #pragma unroll
                for (int dy = 0; dy < 3; ++dy)
                    #pragma unroll
                    for (int dx = 0; dx < 3; ++dx) {
                        float v = s1t[ci][(r+dy)*36 + col + dx];
                        #pragma unroll
                        for (int o = 0; o < 6; ++o)
                            acc[o] = fmaf(v, w2[(o*6 + ci)*9 + dy*3 + dx], acc[o]);
                    }
            #pragma unroll
            for (int o = 0; o < 6; ++o)
                s2t[o][r*36 + col] = fmaxf(acc[o] + s1t[o][(r+1)*36 + col + 1], 0.0f);
        } else {
            #pragma unroll
            for (int o = 0; o < 6; ++o) s2t[o][r*36 + col] = 0.0f;
        }
    }
    __syncthreads();

    // stage B: s3 on the 16x32 tile, v2f over horizontal px pairs
    int r  = threadIdx.x >> 4;          // 0..15
    int cp = threadIdx.x & 15;          // pair index, cols 2cp, 2cp+1
    int gy = R0 + r;
    int pix00 = gy*1280 + C0 + 2*cp;

    v2f acc2[6];
    #pragma unroll
    for (int o = 0; o < 6; ++o) acc2[o] = (v2f){b3[o], b3[o]};
    #pragma unroll
    for (int ci = 0; ci < 6; ++ci)
        #pragma unroll
        for (int dy = 0; dy < 3; ++dy)
            #pragma unroll
            for (int dx = 0; dx < 3; ++dx) {
                int base = (r+dy)*36 + 2*cp + dx;
                v2f v = { s2t[ci][base], s2t[ci][base + 1] };
                float w = w3[(ci)*9 + dy*3 + dx];   // placeholder; replaced per-o below
                (void)w;
                #pragma unroll
                for (int o = 0; o < 6; ++o) {
                    float wo_ = w3[(o*6 + ci)*9 + dy*3 + dx];
                    acc2[o] = __builtin_elementwise_fma(v, (v2f){wo_, wo_}, acc2[o]);
                }
            }

    #pragma unroll
    for (int o = 0; o < 6; ++o) {
        int ctr = (r+1)*36 + 2*cp + 1;
        v2f res = { s2t[o][ctr], s2t[o][ctr + 1] };
        v2f v = acc2[o] + res;
        if (o < 3) {
            *(v2f*)&out[o*921600 + pix00] = v;
        } else {
            v2f sc;
            float ls0 = fminf(fmaxf(v[0], -LSC), LSC);
            float ls1 = fminf(fmaxf(v[1], -LSC), LSC);
            sc[0] = __expf(-0.5f * ls0);
            sc[1] = __expf(-0.5f * ls1);
            *(v2f*)&out[2764800 + (o-3)*921600 + pix00] = sc;
        }
    }
}

// ---------------- host ----------------
extern "C" void kernel_launch(void* const* d_in, const int* in_sizes, int n_in,
                              void* d_out, int out_size, void* d_ws, size_t ws_size,
                              hipStream_t stream)
{
    const float* lat[7];
    for (int i = 0; i < 7; ++i) lat[i] = (const float*)d_in[i];
    const float* arm_w0  = (const float*)d_in[7];
    const float* arm_b0  = (const float*)d_in[8];
    const float* arm_w1  = (const float*)d_in[9];
    const float* arm_b1  = (const float*)d_in[10];
    const float* arm_wo  = (const float*)d_in[11];
    const float* arm_bo  = (const float*)d_in[12];
    const float* pre_k   = (const float*)d_in[13];
    const float* ups_k   = (const float*)d_in[14];
    const float* syn_w0  = (const float*)d_in[15];
    const float* syn_b0  = (const float*)d_in[16];
    const float* syn_w1  = (const float*)d_in[17];
    const float* syn_b1  = (const float*)d_in[18];
    const float* syn_w2  = (const float*)d_in[19];
    const float* syn_b2  = (const float*)d_in[20];
    const float* syn_w3  = (const float*)d_in[21];
    const float* syn_b3  = (const float*)d_in[22];

    float* out = (float*)d_out;
    float* ws  = (float*)d_ws;
    float* rate = out + RATE_OFF;
    float* bsum = ws + BSUM_OFF;

    k_quant<<<dim3(NB_ARM), dim3(256), 0, stream>>>(
        lat[0],lat[1],lat[2],lat[3],lat[4],lat[5],lat[6], ws);

    #define ARM_ARGS ws, arm_w0, arm_b0, arm_w1, arm_b1, arm_wo, arm_bo, rate, bsum
    // fused s=0+s=1: lvl6 + lvl5 -> lvl4 ch1,2 (12 tile blocks) + 1200 ARM
    k_level01<<<dim3(1200+12), dim3(256), 0, stream>>>(
        ws+8190000, ws+8191840, ws+8179200,
        pre_k+0*49, ups_k+0*64, pre_k+1*49, ups_k+1*64,
        ARM_ARGS, 0, 1200);
    // s=2: lvl4 -> lvl3, CH=3, 45 tile blocks + 1200 ARM
    k_level<3,45,80,90,160><<<dim3(1200+45), dim3(256), 0, stream>>>(
        ws+8179200, ws+8121600, pre_k+2*49, ups_k+2*64, ARM_ARGS, 1200, 1200);
    // s=3: CH=4, 240 tile blocks + 1200 ARM
    k_level<4,90,160,180,320><<<dim3(1200+240), dim3(256), 0, stream>>>(
        ws+8121600, ws+7833600, pre_k+3*49, ups_k+3*64, ARM_ARGS, 2400, 1200);
    // s=4: CH=5, 1200 tile blocks + 1200 ARM
    k_level<5,180,320,360,640><<<dim3(1200+1200), dim3(256), 0, stream>>>(
        ws+7833600, ws+6451200, pre_k+4*49, ups_k+4*64, ARM_ARGS, 3600, 1200);
    #undef ARM_ARGS

    // s=5 fused with syn01 (+bpd reduce in block 0): 45x40 = 1800 tiles of 16x32
    k_lvl6syn<<<dim3(1800), dim3(256), 0, stream>>>(
        ws+6451200, ws+0, pre_k+5*49, ups_k+5*64,
        syn_w0, syn_b0, syn_w1, syn_b1, ws + S1_OFF,
        bsum, out + BPD_OFF);

    // fused s2+s3 (uniform weights, LDS staged)
    k_s2s3<<<dim3(1800), dim3(256), 0, stream>>>(
        ws + S1_OFF, syn_w2, syn_b2, syn_w3, syn_b3, out);
}